// Round 2
// baseline (62.917 us; speedup 1.0000x reference)
//
#include <hip/hip_runtime.h>

// ConstrainNet forward:
//   out[0:64]        = V[0, :64] - x0
//   out[t*64 + s]    = dot(AB[s,:], V[t-1,:]) - V[t, s]   for t = 1..T-1
// where AB = [A | B] (64 x 96), V = net_input.reshape(T, 96).
//
// n_state=64, n_input=32, n_all=96, T=128. ~1.5 MFLOP, ~100 KB: the kernel
// is launch-latency-bound; total bench time is dominated by the harness's
// 268 MB workspace re-poison (~39.5 us/iter at 85% HBM peak — rocprof R1).
//
// Structure: 4 timesteps per 256-thread block (one wave per timestep).
//  - V[t-1] is wave-uniform -> compiler promotes its loads to s_load
//    (SGPR broadcast); no LDS staging, no __syncthreads.
//  - All 4 waves of a block read the same A/B rows -> L1-resident reuse.

#define NS 64   // n_state
#define NI 32   // n_input
#define NA 96   // n_all
#define TPB 4   // timesteps (waves) per block

__global__ __launch_bounds__(256) void constrainnet_kernel(
    const float* __restrict__ A,
    const float* __restrict__ B,
    const float* __restrict__ x0,
    const float* __restrict__ V,   // (T, NA) row-major
    float* __restrict__ out,       // (T, NS) row-major
    int T)
{
    const int wave = threadIdx.x >> 6;            // 0..3
    const int s    = threadIdx.x & 63;            // 0..63
    const int t    = blockIdx.x * TPB + wave;     // timestep

    if (t >= T) return;

    if (t == 0) {
        // row-block 0: I @ v0[:NS] - x0  (no barrier anywhere -> safe return)
        out[s] = V[s] - x0[s];
        return;
    }

    // Wave-uniform pointer: loads below compile to scalar (SMEM) broadcasts.
    const float* vprev = V + (size_t)(t - 1) * NA;

    float acc = 0.f;

    // A row s: 16 float4 loads per lane (256 B-aligned rows).
    const float4* a4 = (const float4*)(A + (size_t)s * NS);
    #pragma unroll
    for (int i = 0; i < NS / 4; ++i) {
        float4 av = a4[i];
        acc += av.x * vprev[4 * i + 0];
        acc += av.y * vprev[4 * i + 1];
        acc += av.z * vprev[4 * i + 2];
        acc += av.w * vprev[4 * i + 3];
    }

    // B row s: 8 float4 loads per lane (128 B-aligned rows).
    const float4* b4 = (const float4*)(B + (size_t)s * NI);
    #pragma unroll
    for (int i = 0; i < NI / 4; ++i) {
        float4 bv = b4[i];
        acc += bv.x * vprev[NS + 4 * i + 0];
        acc += bv.y * vprev[NS + 4 * i + 1];
        acc += bv.z * vprev[NS + 4 * i + 2];
        acc += bv.w * vprev[NS + 4 * i + 3];
    }

    // out_rest: prop - V[t, :NS]; lane-coalesced read and store.
    out[(size_t)t * NS + s] = acc - V[(size_t)t * NA + s];
}

extern "C" void kernel_launch(void* const* d_in, const int* in_sizes, int n_in,
                              void* d_out, int out_size, void* d_ws, size_t ws_size,
                              hipStream_t stream) {
    const float* A  = (const float*)d_in[0];
    const float* B  = (const float*)d_in[1];
    const float* x0 = (const float*)d_in[2];
    const float* V  = (const float*)d_in[3];
    float* out = (float*)d_out;

    const int T = in_sizes[3] / NA;   // 12288 / 96 = 128
    const int blocks = (T + TPB - 1) / TPB;

    constrainnet_kernel<<<blocks, 256, 0, stream>>>(A, B, x0, V, out, T);
}